// Round 5
// baseline (127.400 us; speedup 1.0000x reference)
//
#include <hip/hip_runtime.h>

#define DEG 32
#define HID 32
#define CIN 8

typedef float v2f __attribute__((ext_vector_type(2)));
typedef short bf16x8 __attribute__((ext_vector_type(8)));   // 8 bf16 = 4 VGPRs
typedef float f32x16 __attribute__((ext_vector_type(16)));  // MFMA 32x32 C/D

// gelu(t) = t * rcp(1 + exp2(-t*(A + B*t^2)))   [jax tanh-approx, sigmoid form]
#define GELU_A ((float)(2.0 * 1.4426950408889634 * 0.7978845608028654))
#define GELU_B ((float)(2.0 * 1.4426950408889634 * 0.7978845608028654 * 0.044715))

__device__ __forceinline__ unsigned f2bf(float f) {   // fp32 -> bf16 (RNE)
    unsigned b = __float_as_uint(f);
    return (b + 0x7fffu + ((b >> 16) & 1u)) >> 16;
}
__device__ __forceinline__ unsigned pack2(float lo, float hi) {
    return f2bf(lo) | (f2bf(hi) << 16);
}

// Phase 1: x16[n] = bf16(x[n]) (16 B row -> 1.6 MB gather table, L2-resident);
// w1f / w2f = W1 / W2 in MFMA B-fragment order; gtab = 1025-entry gelu table
// over t in [-8, 8] (step 1/64) for the LDS-interp fast path.
__global__ __launch_bounds__(256) void precompute_xw(
    const float* __restrict__ x, const float* __restrict__ W1,
    const float* __restrict__ W2, unsigned* __restrict__ x16,
    unsigned* __restrict__ w1f, unsigned* __restrict__ w2f,
    float* __restrict__ gtab, int N) {
    int tid = blockIdx.x * 256 + threadIdx.x;
    if (blockIdx.x == 0) {
        int t = threadIdx.x;
        if (t < 64) {                       // W1 fragment (K=16 exactly)
            int kb = (t >> 5) * 8, col = t & 31;
            uint4 o;
            o.x = pack2(W1[(kb + 0) * HID + col], W1[(kb + 1) * HID + col]);
            o.y = pack2(W1[(kb + 2) * HID + col], W1[(kb + 3) * HID + col]);
            o.z = pack2(W1[(kb + 4) * HID + col], W1[(kb + 5) * HID + col]);
            o.w = pack2(W1[(kb + 6) * HID + col], W1[(kb + 7) * HID + col]);
            *(uint4*)(w1f + t * 4) = o;
        } else if (t < 192) {               // W2 fragments (K=32 -> 2 frags)
            int u = t - 64;
            int f = u >> 6, l = u & 63;
            int kb = f * 16 + ((l >> 5) * 8), col = l & 31;
            uint4 o;
            o.x = pack2(W2[(kb + 0) * HID + col], W2[(kb + 1) * HID + col]);
            o.y = pack2(W2[(kb + 2) * HID + col], W2[(kb + 3) * HID + col]);
            o.z = pack2(W2[(kb + 4) * HID + col], W2[(kb + 5) * HID + col]);
            o.w = pack2(W2[(kb + 6) * HID + col], W2[(kb + 7) * HID + col]);
            *(uint4*)(w2f + (f * 64 + l) * 4) = o;
        }
        // gelu table: T[k] = gelu(-8 + k/64), k = 0..1024
        for (int k = threadIdx.x; k < 1025; k += 256) {
            float tt = -8.f + (float)k * (1.f / 64.f);
            float x2 = tt * tt;
            float z  = tt * (x2 * (-GELU_B) + (-GELU_A));
            float e  = __builtin_amdgcn_exp2f(z);
            gtab[k]  = tt * __builtin_amdgcn_rcpf(1.0f + e);
        }
    }
    if (tid < N) {
        const float4* xp = (const float4*)(x + (size_t)tid * CIN);
        float4 a = xp[0], b = xp[1];
        uint4 o;
        o.x = pack2(a.x, a.y);  o.y = pack2(a.z, a.w);
        o.z = pack2(b.x, b.y);  o.w = pack2(b.z, b.w);
        *(uint4*)(x16 + (size_t)tid * 4) = o;
    }
}

// Table-interp gelu (bias folded into index) + edge-weighted row-sum.
// C-layout: col=lane&31 (=hid), row(i) = (i&3) + 8*(i>>2) + 4*(lane>>5).
// idxf = (t+8)*64 = fma(acc, 64, b1s);  clamp index, keep raw fraction ->
// free linear extrapolation in the tails (gelu' = 1 / 0 there).
__device__ __forceinline__ float gelu_tab_reduce(const f32x16& acc, const float* swp,
                                                 float b1s, const float* tab) {
    float gacc = 0.f;
#pragma unroll
    for (int q = 0; q < 4; ++q) {
        float4 wq = *(const float4*)(swp + 8 * q);   // rows 8q+4hi .. +3 (broadcast)
        float wqa[4] = {wq.x, wq.y, wq.z, wq.w};
#pragma unroll
        for (int j = 0; j < 4; ++j) {
            int i = q * 4 + j;
            float idxf = fmaf(acc[i], 64.f, b1s);
            float c  = fminf(fmaxf(idxf, 0.f), 1023.f);   // v_med3_f32
            int   ii = (int)c;
            float fl = (float)ii;
            float t0 = tab[ii];                // ds_read2_b32 pair
            float t1 = tab[ii + 1];
            float fr = idxf - fl;
            float g  = fmaf(fr, t1 - t0, t0);
            gacc = fmaf(wqa[j], g, gacc);
        }
    }
    gacc += __shfl_xor(gacc, 32);                // combine the two row-halves
    return gacc;
}

// Fused main: 512-thr block = 8 waves, 2 nodes/wave (16 nodes/block).
// ONE barrier (gelu-table staging); per-wave W2 epilogue via a private LDS
// strip (same-wave write->read, lgkmcnt only).  One nbr load + one wgt
// gather covers both nodes (lo half = node0 edges, hi half = node1; node1's
// list recovered via __shfl_xor 32).  gelu via LDS table interp: kills the
// 2 transcendentals/element that pinned rounds 0-4 at ~44 us.
__global__ __launch_bounds__(512, 4) void git_fused(
    const unsigned* __restrict__ x16, const unsigned* __restrict__ w1f,
    const unsigned* __restrict__ w2f, const float* __restrict__ wgt,
    const float* __restrict__ b1, const float* __restrict__ b2,
    const int* __restrict__ nbr, const float* __restrict__ gtab,
    float* __restrict__ out, int N) {
    __shared__ float stab[1025];       // gelu table
    __shared__ float sw[8 * 64];       // [wave][2 nodes x 32 edge weights]
    // per-wave g strip: 2 valid rows x stride 40 u16 (80 B), strips 160 u16
    // apart.  Epilogue A-reads touch rows 0..31 from each strip base (rows
    // 2+ are don't-care garbage) -> last strip reads up to 7*160+31*40+48 B.
    __shared__ __align__(16) unsigned short sg[2432];

    int t = threadIdx.x;
    int wv = t >> 6;                   // wave 0..7
    int l  = t & 63;
    int l5 = l & 31;
    int hi = l >> 5;
    int nb = blockIdx.x * 16 + wv * 2; // this wave's 2 nodes

    int n0 = min(nb + 0, N - 1), n1 = min(nb + 1, N - 1);

    // dedup'd index/weight gather: one load covers both nodes
    int   J = nbr[(hi ? n1 : n0) * DEG + l5];      // lo: node0 edges, hi: node1
    float W = wgt[J];
    int jsw = __shfl_xor(J, 32);                   // lo lanes get node1's edges

    const bf16x8* x16v = (const bf16x8*)x16;
    bf16x8 A0 = x16v[hi ? n0 : J];                 // lanes 0-31 x_j, 32-63 x_i
    bf16x8 A1 = x16v[hi ? n1 : jsw];
    bf16x8 bfrag = *((const bf16x8*)w1f + l);      // shared W1 fragment
    float b1s = fmaf(b1[l5], 64.f, 512.f);         // (b1+8)*64: table index bias

    // stage gelu table (block-wide, once)
    stab[t]       = gtab[t];
    stab[t + 512] = gtab[t + 512];
    if (t == 0) stab[1024] = gtab[1024];

    // stage edge weights for broadcast (own wave strip only)
    float* swv = &sw[wv * 64];
    swv[hi * 32 + l5] = W;            // node0 w at [0..31], node1 at [32..63]

    // one butterfly: lo half sums node0 weights, hi half node1
    float ws = W;
    ws += __shfl_xor(ws, 1);  ws += __shfl_xor(ws, 2);
    ws += __shfl_xor(ws, 4);  ws += __shfl_xor(ws, 8);
    ws += __shfl_xor(ws, 16);

    f32x16 z0 = {}, z1 = {};
    f32x16 a0 = __builtin_amdgcn_mfma_f32_32x32x16_bf16(A0, bfrag, z0, 0, 0, 0);
    f32x16 a1 = __builtin_amdgcn_mfma_f32_32x32x16_bf16(A1, bfrag, z1, 0, 0, 0);

    __syncthreads();                   // table staged (gathers already consumed)

    float g0 = gelu_tab_reduce(a0, swv + hi * 4,      b1s, stab);
    float g1 = gelu_tab_reduce(a1, swv + 32 + hi * 4, b1s, stab);

    // ---- stage the 2 g rows in this wave's private strip ----
    // g0/g1 are complete in all 64 lanes: hi=0 lanes write row0, hi=1 row1.
    unsigned short* sgw = &sg[wv * 160];           // 2 rows x 40 u16
    float ga = hi ? g1 : g0;
    sgw[hi * 40 + l5] = (unsigned short)f2bf(ga);

    // ---- per-wave epilogue: out = (G @ W2 + ws x b2)/32 for 2 nodes ----
    // A rows 0..1 valid; rows 2..31 read don't-care LDS (their D rows unused).
    bf16x8 eb1 = *((const bf16x8*)w2f + l);        // W2 frag k 0-15
    bf16x8 eb2 = *((const bf16x8*)w2f + 64 + l);   // W2 frag k 16-31
    float myb2 = b2[l5];
    const char* sgb = (const char*)sgw;
    bf16x8 ea1 = *(const bf16x8*)(sgb + l5 * 80 + hi * 16);        // k 0-15
    bf16x8 ea2 = *(const bf16x8*)(sgb + l5 * 80 + 32 + hi * 16);   // k 16-31
    f32x16 zz = {};
    f32x16 acc = __builtin_amdgcn_mfma_f32_32x32x16_bf16(ea1, eb1, zz, 0, 0, 0);
    acc = __builtin_amdgcn_mfma_f32_32x32x16_bf16(ea2, eb2, acc, 0, 0, 0);

    float wsx = __shfl_xor(ws, 32);    // lo lanes get node1's weight sum
    // C rows: node0 -> r0 = acc[0] (i=0,hi=0); node1 -> r1 = acc[1] (i=1,hi=0)
    if (hi == 0) {
        if (nb < N)
            out[(size_t)n0 * HID + l5] = fmaf(ws,  myb2, acc[0]) * (1.0f / DEG);
        if (nb + 1 < N)
            out[(size_t)n1 * HID + l5] = fmaf(wsx, myb2, acc[1]) * (1.0f / DEG);
    }
}

// Fallback if d_ws too small: single fused kernel (no workspace tables).
__global__ __launch_bounds__(256) void fused_fallback(
    const float* __restrict__ x, const float* __restrict__ wgt,
    const float* __restrict__ W1, const float* __restrict__ b1,
    const float* __restrict__ W2, const float* __restrict__ b2,
    const int* __restrict__ nbr, float* __restrict__ out, int N) {
    __shared__ float sW2[HID * HID];
    __shared__ float sb2[HID];
    __shared__ int2  sp[8 * DEG];
    int t = threadIdx.x;
#pragma unroll
    for (int i = 0; i < 4; ++i) sW2[t + i * 256] = W2[t + i * 256];
    if (t < HID) sb2[t] = b2[t];
    int slot = t >> 5, hid = t & 31;
    int node = blockIdx.x * 8 + slot;
    bool valid = node < N;
    int nc = valid ? node : (N - 1);
    int   j_own = nbr[nc * DEG + hid];
    float w_own = wgt[j_own];
    sp[slot * DEG + hid] = make_int2(j_own * (CIN * 4), __float_as_int(w_own));
    const float4* xip = (const float4*)(x + (size_t)nc * CIN);
    float4 xa = xip[0], xb = xip[1];
    float w1t[8];
#pragma unroll
    for (int k = 0; k < 8; ++k) w1t[k] = W1[k * HID + hid];
    float vb = b1[hid];
    vb = fmaf(xa.x, W1[ 8 * HID + hid], vb);
    vb = fmaf(xa.y, W1[ 9 * HID + hid], vb);
    vb = fmaf(xa.z, W1[10 * HID + hid], vb);
    vb = fmaf(xa.w, W1[11 * HID + hid], vb);
    vb = fmaf(xb.x, W1[12 * HID + hid], vb);
    vb = fmaf(xb.y, W1[13 * HID + hid], vb);
    vb = fmaf(xb.z, W1[14 * HID + hid], vb);
    vb = fmaf(xb.w, W1[15 * HID + hid], vb);
    float ws = w_own;
    ws += __shfl_xor(ws, 1);  ws += __shfl_xor(ws, 2);
    ws += __shfl_xor(ws, 4);  ws += __shfl_xor(ws, 8);
    ws += __shfl_xor(ws, 16);
    __syncthreads();
    const char* xbytes = (const char*)x;
    const int2* myp = &sp[slot * DEG];
    float g = 0.f;
#pragma unroll 8
    for (int e = 0; e < DEG; ++e) {
        int2  p  = myp[e];
        float wjv = __int_as_float(p.y);
        const float4* xjp = (const float4*)(xbytes + (unsigned)p.x);
        float4 a = xjp[0], b = xjp[1];
        float tin = vb;
        tin = fmaf(a.x, w1t[0], tin); tin = fmaf(a.y, w1t[1], tin);
        tin = fmaf(a.z, w1t[2], tin); tin = fmaf(a.w, w1t[3], tin);
        tin = fmaf(b.x, w1t[4], tin); tin = fmaf(b.y, w1t[5], tin);
        tin = fmaf(b.z, w1t[6], tin); tin = fmaf(b.w, w1t[7], tin);
        float x2 = tin * tin;
        float z  = tin * fmaf(GELU_B, x2, GELU_A);
        float e2 = __builtin_amdgcn_exp2f(z);
        float r  = __builtin_amdgcn_rcpf(1.0f + e2);
        g = fmaf(wjv, fmaf(-tin, r, tin), g);
    }
    float acc = 0.f;
#pragma unroll
    for (int h = 0; h < HID; ++h) {
        float gh = __shfl(g, h, 32);
        acc = fmaf(gh, sW2[h * HID + hid], acc);
    }
    if (valid) out[(size_t)node * HID + hid] = fmaf(ws, sb2[hid], acc) * (1.0f / DEG);
}

extern "C" void kernel_launch(void* const* d_in, const int* in_sizes, int n_in,
                              void* d_out, int out_size, void* d_ws, size_t ws_size,
                              hipStream_t stream) {
    const float* x   = (const float*)d_in[0];
    const float* wq  = (const float*)d_in[1];
    const float* W1  = (const float*)d_in[2];
    const float* b1  = (const float*)d_in[3];
    const float* W2  = (const float*)d_in[4];
    const float* b2  = (const float*)d_in[5];
    const int*   nbr = (const int*)d_in[6];
    float* out = (float*)d_out;

    int N = in_sizes[1];                        // in_weights has N elements

    size_t off_x16 = 0;
    size_t off_w1  = (off_x16 + (size_t)N * 16 + 255) & ~(size_t)255;
    size_t off_w2  = off_w1 + 1024;
    size_t off_tab = off_w2 + 2048;
    size_t need    = off_tab + 4 * 1056;        // 1025 entries + slack

    if (ws_size >= need) {
        unsigned* x16 = (unsigned*)((char*)d_ws + off_x16);
        unsigned* w1f = (unsigned*)((char*)d_ws + off_w1);
        unsigned* w2f = (unsigned*)((char*)d_ws + off_w2);
        float*   gtab = (float*)((char*)d_ws + off_tab);

        int blocks_pre = (N + 255) / 256;
        precompute_xw<<<blocks_pre, 256, 0, stream>>>(x, W1, W2, x16, w1f, w2f,
                                                      gtab, N);

        int blocks_main = (N + 15) / 16;        // 16 nodes per 512-thread block
        git_fused<<<blocks_main, 512, 0, stream>>>(x16, w1f, w2f, wq, b1, b2,
                                                   nbr, gtab, out, N);
    } else {
        int blocks = (N + 7) / 8;
        fused_fallback<<<blocks, 256, 0, stream>>>(x, wq, W1, b1, W2, b2, nbr, out, N);
    }
}

// Round 6
// 116.152 us; speedup vs baseline: 1.0968x; 1.0968x over previous
//
#include <hip/hip_runtime.h>

#define DEG 32
#define HID 32
#define CIN 8

typedef float v2f __attribute__((ext_vector_type(2)));
typedef short bf16x8 __attribute__((ext_vector_type(8)));   // 8 bf16 = 4 VGPRs
typedef float f32x16 __attribute__((ext_vector_type(16)));  // MFMA 32x32 C/D

// gelu(t) = t * rcp(1 + exp2(-t*(A + B*t^2)))   [jax tanh-approx, sigmoid form]
#define GELU_A ((float)(2.0 * 1.4426950408889634 * 0.7978845608028654))
#define GELU_B ((float)(2.0 * 1.4426950408889634 * 0.7978845608028654 * 0.044715))

__device__ __forceinline__ unsigned f2bf(float f) {   // fp32 -> bf16 (RNE)
    unsigned b = __float_as_uint(f);
    return (b + 0x7fffu + ((b >> 16) & 1u)) >> 16;
}
__device__ __forceinline__ unsigned pack2(float lo, float hi) {
    return f2bf(lo) | (f2bf(hi) << 16);
}

// Phase 1: x16[n] = bf16(x[n]) (16 B row -> 1.6 MB gather table, L2-resident);
// w1f / w2f = W1 / W2 in MFMA B-fragment order (frag f: lane l holds
// B[k = f*16 + (l>>5)*8 + j][col = l&31], j=0..7).
__global__ __launch_bounds__(256) void precompute_xw(
    const float* __restrict__ x, const float* __restrict__ W1,
    const float* __restrict__ W2, unsigned* __restrict__ x16,
    unsigned* __restrict__ w1f, unsigned* __restrict__ w2f, int N) {
    int tid = blockIdx.x * 256 + threadIdx.x;
    if (blockIdx.x == 0) {
        int t = threadIdx.x;
        if (t < 64) {                       // W1 fragment (K=16 exactly)
            int kb = (t >> 5) * 8, col = t & 31;
            uint4 o;
            o.x = pack2(W1[(kb + 0) * HID + col], W1[(kb + 1) * HID + col]);
            o.y = pack2(W1[(kb + 2) * HID + col], W1[(kb + 3) * HID + col]);
            o.z = pack2(W1[(kb + 4) * HID + col], W1[(kb + 5) * HID + col]);
            o.w = pack2(W1[(kb + 6) * HID + col], W1[(kb + 7) * HID + col]);
            *(uint4*)(w1f + t * 4) = o;
        } else if (t < 192) {               // W2 fragments (K=32 -> 2 frags)
            int u = t - 64;
            int f = u >> 6, l = u & 63;
            int kb = f * 16 + ((l >> 5) * 8), col = l & 31;
            uint4 o;
            o.x = pack2(W2[(kb + 0) * HID + col], W2[(kb + 1) * HID + col]);
            o.y = pack2(W2[(kb + 2) * HID + col], W2[(kb + 3) * HID + col]);
            o.z = pack2(W2[(kb + 4) * HID + col], W2[(kb + 5) * HID + col]);
            o.w = pack2(W2[(kb + 6) * HID + col], W2[(kb + 7) * HID + col]);
            *(uint4*)(w2f + (f * 64 + l) * 4) = o;
        }
    }
    if (tid < N) {
        const float4* xp = (const float4*)(x + (size_t)tid * CIN);
        float4 a = xp[0], b = xp[1];
        uint4 o;
        o.x = pack2(a.x, a.y);  o.y = pack2(a.z, a.w);
        o.z = pack2(b.x, b.y);  o.w = pack2(b.z, b.w);
        *(uint4*)(x16 + (size_t)tid * 4) = o;
    }
}

// gelu (with bias) + edge-weighted row-sum over one node's C fragment.
// C-layout: col=lane&31 (=hid), row(i) = (i&3) + 8*(i>>2) + 4*(lane>>5).
// Weights consumed quad-at-a-time (LDS float4 broadcast per half).
__device__ __forceinline__ float gelu_reduce(const f32x16& acc, const float* swp,
                                             float b1v) {
    v2f gacc = {0.f, 0.f};
#pragma unroll
    for (int q = 0; q < 4; ++q) {
        float4 wq = *(const float4*)(swp + 8 * q);   // rows 8q+4hi .. +3 (broadcast)
#pragma unroll
        for (int h = 0; h < 2; ++h) {
            int i = q * 4 + h * 2;
            v2f tt = {acc[i] + b1v, acc[i + 1] + b1v};
            v2f x2 = tt * tt;
            v2f zz = tt * (x2 * (-GELU_B) + (-GELU_A));
            v2f ee;
            ee.x = __builtin_amdgcn_exp2f(zz.x);  ee.y = __builtin_amdgcn_exp2f(zz.y);
            v2f dd = ee + 1.0f;
            v2f rr;
            rr.x = __builtin_amdgcn_rcpf(dd.x);   rr.y = __builtin_amdgcn_rcpf(dd.y);
            v2f wp = h ? (v2f){wq.z, wq.w} : (v2f){wq.x, wq.y};
            gacc += wp * (tt * rr);                  // gelu = t*sigmoid; exact limits
        }
    }
    float g = gacc.x + gacc.y;
    g += __shfl_xor(g, 32);                      // combine the two row-halves
    return g;
}

// Fused main: 256-thr block = 4 FULLY INDEPENDENT waves; each wave loops over
// NPAIR=4 node-pairs (8 nodes/wave, 32/block, 3125 blocks).  ZERO barriers;
// per-wave W2 epilogue via a private LDS strip (same-wave write->read).
// Rounds 0/3/4 all ran at a constant ~73k threads/us regardless of structure
// -> per-thread work too small; the 8x-nodes-per-thread loop amortizes the
// serial nbr->wgt/x16 gather chain and cuts total threads 4x.  All 4 nbr
// rows issued up-front; depth-1 prefetch of next pair's wgt/x16 gathers.
__global__ __launch_bounds__(256) void git_fused(
    const unsigned* __restrict__ x16, const unsigned* __restrict__ w1f,
    const unsigned* __restrict__ w2f, const float* __restrict__ wgt,
    const float* __restrict__ b1, const float* __restrict__ b2,
    const int* __restrict__ nbr, float* __restrict__ out, int N) {
    __shared__ float sw[4 * 2 * 64];   // [wave][buf][2 nodes x 32 edge weights]
    // per-wave g strip: 2 valid rows x stride 40 u16 (80 B).  Epilogue
    // A-reads touch rows 0..31 from each strip base (rows 2+ are don't-care
    // garbage) -> last strip (wv=3, base 480) reads up to 480+31*40+24+8.
    __shared__ __align__(16) unsigned short sg[2432];

    int t = threadIdx.x;
    int wv = t >> 6;                   // wave 0..3
    int l  = t & 63;
    int l5 = l & 31;
    int hi = l >> 5;
    int nb = blockIdx.x * 32 + wv * 8; // this wave's 8 nodes (4 pairs)

    const bf16x8* x16v = (const bf16x8*)x16;
    bf16x8 bfrag = *((const bf16x8*)w1f + l);      // shared W1 fragment
    bf16x8 eb1   = *((const bf16x8*)w2f + l);      // W2 frag k 0-15
    bf16x8 eb2   = *((const bf16x8*)w2f + 64 + l); // W2 frag k 16-31
    float myb1 = b1[l5];
    float myb2 = b2[l5];

    // ---- all 4 nbr rows in flight at once (head of every gather chain) ----
    int J[4];
#pragma unroll
    for (int k = 0; k < 4; ++k) {
        int n0 = min(nb + 2 * k,     N - 1);
        int n1 = min(nb + 2 * k + 1, N - 1);
        J[k] = nbr[(hi ? n1 : n0) * DEG + l5];     // lo: even node, hi: odd
    }

    // ---- pair-0 gathers ----
    float W = wgt[J[0]];
    int jsw0 = __shfl_xor(J[0], 32);               // lo lanes get odd node's edges
    bf16x8 A0 = x16v[hi ? min(nb,     N - 1) : J[0]];   // lanes 0-31 x_j, 32-63 x_i
    bf16x8 A1 = x16v[hi ? min(nb + 1, N - 1) : jsw0];

    unsigned short* sgw = &sg[wv * 160];           // 2 rows x 40 u16
    const char* sgb = (const char*)sgw;

#pragma unroll
    for (int k = 0; k < 4; ++k) {
        // ---- prefetch pair k+1 (in flight across this pair's compute) ----
        float  Wn = 0.f;
        bf16x8 A0n = {}, A1n = {};
        if (k < 3) {
            Wn = wgt[J[k + 1]];
            int jswn = __shfl_xor(J[k + 1], 32);
            A0n = x16v[hi ? min(nb + 2 * k + 2, N - 1) : J[k + 1]];
            A1n = x16v[hi ? min(nb + 2 * k + 3, N - 1) : jswn];
        }

        // ---- compute pair k ----
        float* swv = &sw[wv * 128 + (k & 1) * 64]; // double-buffered weight strip
        swv[hi * 32 + l5] = W;        // even node w at [0..31], odd at [32..63]

        float ws = W;                 // lo half sums even node, hi half odd
        ws += __shfl_xor(ws, 1);  ws += __shfl_xor(ws, 2);
        ws += __shfl_xor(ws, 4);  ws += __shfl_xor(ws, 8);
        ws += __shfl_xor(ws, 16);

        f32x16 z0 = {}, z1 = {};
        f32x16 a0 = __builtin_amdgcn_mfma_f32_32x32x16_bf16(A0, bfrag, z0, 0, 0, 0);
        f32x16 a1 = __builtin_amdgcn_mfma_f32_32x32x16_bf16(A1, bfrag, z1, 0, 0, 0);

        float g0 = gelu_reduce(a0, swv + hi * 4,      myb1);
        float g1 = gelu_reduce(a1, swv + 32 + hi * 4, myb1);

        // stage the 2 g rows in this wave's private strip (hi=0 row0, hi=1 row1)
        float ga = hi ? g1 : g0;
        sgw[hi * 40 + l5] = (unsigned short)f2bf(ga);

        // per-wave epilogue: out = (G @ W2 + ws x b2)/32 for 2 nodes.
        // A rows 0..1 valid; rows 2..31 read don't-care LDS (D rows unused).
        bf16x8 ea1 = *(const bf16x8*)(sgb + l5 * 80 + hi * 16);        // k 0-15
        bf16x8 ea2 = *(const bf16x8*)(sgb + l5 * 80 + 32 + hi * 16);   // k 16-31
        f32x16 zz = {};
        f32x16 acc = __builtin_amdgcn_mfma_f32_32x32x16_bf16(ea1, eb1, zz, 0, 0, 0);
        acc = __builtin_amdgcn_mfma_f32_32x32x16_bf16(ea2, eb2, acc, 0, 0, 0);

        float wsx = __shfl_xor(ws, 32);   // lo lanes get odd node's weight sum
        // C rows: even node -> acc[0] (i=0,hi=0); odd node -> acc[1] (i=1,hi=0)
        if (hi == 0) {
            int n0 = nb + 2 * k, n1 = nb + 2 * k + 1;
            if (n0 < N)
                out[(size_t)n0 * HID + l5] = fmaf(ws,  myb2, acc[0]) * (1.0f / DEG);
            if (n1 < N)
                out[(size_t)n1 * HID + l5] = fmaf(wsx, myb2, acc[1]) * (1.0f / DEG);
        }

        // rotate pipeline state
        W = Wn;  A0 = A0n;  A1 = A1n;
    }
}

// Fallback if d_ws too small: single fused kernel (no workspace tables).
__global__ __launch_bounds__(256) void fused_fallback(
    const float* __restrict__ x, const float* __restrict__ wgt,
    const float* __restrict__ W1, const float* __restrict__ b1,
    const float* __restrict__ W2, const float* __restrict__ b2,
    const int* __restrict__ nbr, float* __restrict__ out, int N) {
    __shared__ float sW2[HID * HID];
    __shared__ float sb2[HID];
    __shared__ int2  sp[8 * DEG];
    int t = threadIdx.x;
#pragma unroll
    for (int i = 0; i < 4; ++i) sW2[t + i * 256] = W2[t + i * 256];
    if (t < HID) sb2[t] = b2[t];
    int slot = t >> 5, hid = t & 31;
    int node = blockIdx.x * 8 + slot;
    bool valid = node < N;
    int nc = valid ? node : (N - 1);
    int   j_own = nbr[nc * DEG + hid];
    float w_own = wgt[j_own];
    sp[slot * DEG + hid] = make_int2(j_own * (CIN * 4), __float_as_int(w_own));
    const float4* xip = (const float4*)(x + (size_t)nc * CIN);
    float4 xa = xip[0], xb = xip[1];
    float w1t[8];
#pragma unroll
    for (int k = 0; k < 8; ++k) w1t[k] = W1[k * HID + hid];
    float vb = b1[hid];
    vb = fmaf(xa.x, W1[ 8 * HID + hid], vb);
    vb = fmaf(xa.y, W1[ 9 * HID + hid], vb);
    vb = fmaf(xa.z, W1[10 * HID + hid], vb);
    vb = fmaf(xa.w, W1[11 * HID + hid], vb);
    vb = fmaf(xb.x, W1[12 * HID + hid], vb);
    vb = fmaf(xb.y, W1[13 * HID + hid], vb);
    vb = fmaf(xb.z, W1[14 * HID + hid], vb);
    vb = fmaf(xb.w, W1[15 * HID + hid], vb);
    float ws = w_own;
    ws += __shfl_xor(ws, 1);  ws += __shfl_xor(ws, 2);
    ws += __shfl_xor(ws, 4);  ws += __shfl_xor(ws, 8);
    ws += __shfl_xor(ws, 16);
    __syncthreads();
    const char* xbytes = (const char*)x;
    const int2* myp = &sp[slot * DEG];
    float g = 0.f;
#pragma unroll 8
    for (int e = 0; e < DEG; ++e) {
        int2  p  = myp[e];
        float wjv = __int_as_float(p.y);
        const float4* xjp = (const float4*)(xbytes + (unsigned)p.x);
        float4 a = xjp[0], b = xjp[1];
        float tin = vb;
        tin = fmaf(a.x, w1t[0], tin); tin = fmaf(a.y, w1t[1], tin);
        tin = fmaf(a.z, w1t[2], tin); tin = fmaf(a.w, w1t[3], tin);
        tin = fmaf(b.x, w1t[4], tin); tin = fmaf(b.y, w1t[5], tin);
        tin = fmaf(b.z, w1t[6], tin); tin = fmaf(b.w, w1t[7], tin);
        float x2 = tin * tin;
        float z  = tin * fmaf(GELU_B, x2, GELU_A);
        float e2 = __builtin_amdgcn_exp2f(z);
        float r  = __builtin_amdgcn_rcpf(1.0f + e2);
        g = fmaf(wjv, fmaf(-tin, r, tin), g);
    }
    float acc = 0.f;
#pragma unroll
    for (int h = 0; h < HID; ++h) {
        float gh = __shfl(g, h, 32);
        acc = fmaf(gh, sW2[h * HID + hid], acc);
    }
    if (valid) out[(size_t)node * HID + hid] = fmaf(ws, sb2[hid], acc) * (1.0f / DEG);
}

extern "C" void kernel_launch(void* const* d_in, const int* in_sizes, int n_in,
                              void* d_out, int out_size, void* d_ws, size_t ws_size,
                              hipStream_t stream) {
    const float* x   = (const float*)d_in[0];
    const float* wq  = (const float*)d_in[1];
    const float* W1  = (const float*)d_in[2];
    const float* b1  = (const float*)d_in[3];
    const float* W2  = (const float*)d_in[4];
    const float* b2  = (const float*)d_in[5];
    const int*   nbr = (const int*)d_in[6];
    float* out = (float*)d_out;

    int N = in_sizes[1];                        // in_weights has N elements

    size_t off_x16 = 0;
    size_t off_w1  = (off_x16 + (size_t)N * 16 + 255) & ~(size_t)255;
    size_t off_w2  = off_w1 + 1024;
    size_t need    = off_w2 + 2048;

    if (ws_size >= need) {
        unsigned* x16 = (unsigned*)((char*)d_ws + off_x16);
        unsigned* w1f = (unsigned*)((char*)d_ws + off_w1);
        unsigned* w2f = (unsigned*)((char*)d_ws + off_w2);

        int blocks_pre = (N + 255) / 256;
        precompute_xw<<<blocks_pre, 256, 0, stream>>>(x, W1, W2, x16, w1f, w2f, N);

        int blocks_main = (N + 31) / 32;        // 32 nodes per 256-thread block
        git_fused<<<blocks_main, 256, 0, stream>>>(x16, w1f, w2f, wq, b1, b2,
                                                   nbr, out, N);
    } else {
        int blocks = (N + 7) / 8;
        fused_fallback<<<blocks, 256, 0, stream>>>(x, wq, W1, b1, W2, b2, nbr, out, N);
    }
}